// Round 15
// baseline (733.161 us; speedup 1.0000x reference)
//
#include <hip/hip_runtime.h>

#define N_NODES 50000
#define N_EDGES 600000
#define HID 128
#define N_LAYERS 5
#define SCAN_BLK 256
#define N_SCAN_BLOCKS ((N_NODES + SCAN_BLK - 1) / SCAN_BLK)   // 196
#define NH ((size_t)N_NODES * HID)
#define NSLICE 8
#define SL_STRIDE ((size_t)N_NODES * 16)   // u32 per slice

typedef unsigned int u32;
typedef _Float16 half8 __attribute__((ext_vector_type(8)));
typedef _Float16 half4 __attribute__((ext_vector_type(4)));
typedef _Float16 h2 __attribute__((ext_vector_type(2)));
typedef float f32x4 __attribute__((ext_vector_type(4)));
typedef u32 u32x8 __attribute__((ext_vector_type(8)));

// packed split format: one u32 per feature; h[0]=fp16 hi, h[1]=fp16 residual
union PK { u32 u; _Float16 h[2]; };

__device__ inline u32 pack_split(float v) {
    PK r;
    r.h[0] = (_Float16)v;
    r.h[1] = (_Float16)(v - (float)r.h[0]);
    return r.u;
}
// acc += hi + lo in ONE VALU op: v_dot2_f32_f16 with b=(1,1)
__device__ inline float dot2acc(u32 p, float acc) {
    h2 a = __builtin_bit_cast(h2, p);
    h2 ones; ones[0] = (_Float16)1.0f; ones[1] = (_Float16)1.0f;
    return __builtin_amdgcn_fdot2(a, ones, acc, false);
}

// ---------------- CSR build + degree sort ----------------

__global__ void zero_deg(int* __restrict__ deg, int* __restrict__ hist) {
    int i = blockIdx.x * blockDim.x + threadIdx.x;
    if (i < N_NODES) deg[i] = 0;
    if (i < 256) hist[i] = 0;
}

__global__ void deg_count(const int* __restrict__ dst, int* __restrict__ deg) {
    int e = blockIdx.x * blockDim.x + threadIdx.x;
    if (e < N_EDGES) atomicAdd(&deg[dst[e]], 1);
}

__global__ __launch_bounds__(SCAN_BLK) void deg_reduce(const int* __restrict__ deg,
                                                       int* __restrict__ block_sums) {
    __shared__ int s[SCAN_BLK];
    int i = blockIdx.x * SCAN_BLK + threadIdx.x;
    int v = (i < N_NODES) ? deg[i] : 0;
    s[threadIdx.x] = v;
    __syncthreads();
    for (int off = SCAN_BLK / 2; off > 0; off >>= 1) {
        if (threadIdx.x < off) s[threadIdx.x] += s[threadIdx.x + off];
        __syncthreads();
    }
    if (threadIdx.x == 0) block_sums[blockIdx.x] = s[0];
}

__global__ __launch_bounds__(SCAN_BLK) void scan_partials(const int* __restrict__ block_sums,
                                                          int* __restrict__ block_off) {
    __shared__ int s[SCAN_BLK];
    int t = threadIdx.x;
    int v = (t < N_SCAN_BLOCKS) ? block_sums[t] : 0;
    s[t] = v;
    __syncthreads();
    for (int off = 1; off < SCAN_BLK; off <<= 1) {
        int u = (t >= off) ? s[t - off] : 0;
        __syncthreads();
        s[t] += u;
        __syncthreads();
    }
    if (t < N_SCAN_BLOCKS) block_off[t] = s[t] - v;
}

__global__ __launch_bounds__(SCAN_BLK) void scan_write(const int* __restrict__ deg,
        const int* __restrict__ block_off, int* __restrict__ row_ptr,
        int* __restrict__ cursor, float* __restrict__ deg_inv,
        int* __restrict__ hist) {
    __shared__ int s[SCAN_BLK];
    int t = threadIdx.x;
    int i = blockIdx.x * SCAN_BLK + t;
    int v = (i < N_NODES) ? deg[i] : 0;
    s[t] = v;
    __syncthreads();
    for (int off = 1; off < SCAN_BLK; off <<= 1) {
        int u = (t >= off) ? s[t - off] : 0;
        __syncthreads();
        s[t] += u;
        __syncthreads();
    }
    int excl = s[t] - v + block_off[blockIdx.x];
    if (i < N_NODES) {
        row_ptr[i] = excl;
        cursor[i]  = excl;
        deg_inv[i] = 1.0f / (float)max(v, 1);
        atomicAdd(&hist[min(v, 255)], 1);     // degree histogram for sort
    }
    if (i == N_NODES) row_ptr[N_NODES] = excl;
}

// exclusive scan of 256 degree bins -> bin cursors
__global__ __launch_bounds__(256) void hist_scan(const int* __restrict__ hist,
                                                 int* __restrict__ bin_cur) {
    __shared__ int s[256];
    int t = threadIdx.x;
    int v = hist[t];
    s[t] = v;
    __syncthreads();
    for (int off = 1; off < 256; off <<= 1) {
        int u = (t >= off) ? s[t - off] : 0;
        __syncthreads();
        s[t] += u;
        __syncthreads();
    }
    bin_cur[t] = s[t] - v;
}

// scatter node ids into degree-sorted order
__global__ void perm_scatter(const int* __restrict__ deg, int* __restrict__ bin_cur,
                             int* __restrict__ node_perm) {
    int i = blockIdx.x * blockDim.x + threadIdx.x;
    if (i < N_NODES) {
        int b = min(deg[i], 255);
        int pos = atomicAdd(&bin_cur[b], 1);
        node_perm[pos] = i;
    }
}

__global__ void fill_csr(const int* __restrict__ src, const int* __restrict__ dst,
                         int* __restrict__ cursor, int* __restrict__ col) {
    int e = blockIdx.x * blockDim.x + threadIdx.x;
    if (e < N_EDGES) {
        int d = dst[e];
        int pos = atomicAdd(&cursor[d], 1);
        col[pos] = src[e];
    }
}

// ---------------- merged split kernel ----------------
#define W_N4 20480
#define X_Q 1600000

__global__ void split_all(const float* __restrict__ Wl, const float* __restrict__ Wr,
                          const float* __restrict__ x,
                          _Float16* __restrict__ Wlh, _Float16* __restrict__ Wll,
                          _Float16* __restrict__ Wrh, _Float16* __restrict__ Wrl,
                          u32* __restrict__ hp) {
    int i = blockIdx.x * blockDim.x + threadIdx.x;
    if (i < 2 * W_N4) {
        const float* srcp = (i < W_N4) ? Wl : Wr;
        _Float16* hi = (i < W_N4) ? Wlh : Wrh;
        _Float16* lo = (i < W_N4) ? Wll : Wrl;
        int k = (i < W_N4) ? i : i - W_N4;
        float4 v = *(const float4*)(srcp + (size_t)k * 4);
        half4 h, l;
        h.x = (_Float16)v.x; l.x = (_Float16)(v.x - (float)h.x);
        h.y = (_Float16)v.y; l.y = (_Float16)(v.y - (float)h.y);
        h.z = (_Float16)v.z; l.z = (_Float16)(v.z - (float)h.z);
        h.w = (_Float16)v.w; l.w = (_Float16)(v.w - (float)h.w);
        *(half4*)(hi + (size_t)k * 4) = h;
        *(half4*)(lo + (size_t)k * 4) = l;
    } else {
        int iq = i - 2 * W_N4;
        if (iq >= X_Q) return;
        int n = iq >> 5;          // node
        int c = iq & 31;          // quad within row
        float4 v = *(const float4*)(x + (size_t)n * HID + c * 4);
        uint4 r;
        r.x = pack_split(v.x); r.y = pack_split(v.y);
        r.z = pack_split(v.z); r.w = pack_split(v.w);
        int slice = c >> 2, rem = (c & 3) * 4;
        *(uint4*)(hp + (size_t)slice * SL_STRIDE + (size_t)n * 16 + rem) = r;
    }
}

// ---- slice-major mean aggregation: 4-lane group per (node,slice) ----
// Groups take nodes in DEGREE-SORTED order (node_perm) so the 16 groups of a
// wave have near-equal trip counts -> minimal exec-mask divergence.
// Lane q owns u32s [4q,4q+4); 8-deep edge unroll, fdot2 accumulate.
// slice = blockIdx&7 -> XCD pinning: each XCD's L2 caches one 3.2MB slice.

__global__ __launch_bounds__(256) void aggregate_d2(const u32* __restrict__ hp,
        const int* __restrict__ row_ptr, const int* __restrict__ col,
        const int* __restrict__ node_perm, const float* __restrict__ deg_inv,
        u32* __restrict__ mp) {
    const int wave  = threadIdx.x >> 6;
    const int lane  = threadIdx.x & 63;
    const int grp   = lane >> 2;          // 16 node-groups per wave
    const int q4    = (lane & 3) * 4;     // u32 offset of this lane's quad
    const int slice = blockIdx.x & 7;
    const int idx   = (blockIdx.x >> 3) * 64 + wave * 16 + grp;
    if (idx >= N_NODES) return;
    const int node = node_perm[idx];
    const u32* hsl = hp + (size_t)slice * SL_STRIDE + q4;
    const int beg = row_ptr[node], end = row_ptr[node + 1];
    float a0 = 0.f, a1 = 0.f, a2 = 0.f, a3 = 0.f;
    int e = beg;
    for (; e + 7 < end; e += 8) {         // 8 row-lines in flight per group
        int s0 = col[e],     s1 = col[e + 1], s2 = col[e + 2], s3 = col[e + 3];
        int s4 = col[e + 4], s5 = col[e + 5], s6 = col[e + 6], s7 = col[e + 7];
        uint4 v0 = *(const uint4*)(hsl + (unsigned)s0 * 16u);
        uint4 v1 = *(const uint4*)(hsl + (unsigned)s1 * 16u);
        uint4 v2 = *(const uint4*)(hsl + (unsigned)s2 * 16u);
        uint4 v3 = *(const uint4*)(hsl + (unsigned)s3 * 16u);
        uint4 v4 = *(const uint4*)(hsl + (unsigned)s4 * 16u);
        uint4 v5 = *(const uint4*)(hsl + (unsigned)s5 * 16u);
        uint4 v6 = *(const uint4*)(hsl + (unsigned)s6 * 16u);
        uint4 v7 = *(const uint4*)(hsl + (unsigned)s7 * 16u);
        a0 = dot2acc(v0.x, a0); a1 = dot2acc(v0.y, a1);
        a2 = dot2acc(v0.z, a2); a3 = dot2acc(v0.w, a3);
        a0 = dot2acc(v1.x, a0); a1 = dot2acc(v1.y, a1);
        a2 = dot2acc(v1.z, a2); a3 = dot2acc(v1.w, a3);
        a0 = dot2acc(v2.x, a0); a1 = dot2acc(v2.y, a1);
        a2 = dot2acc(v2.z, a2); a3 = dot2acc(v2.w, a3);
        a0 = dot2acc(v3.x, a0); a1 = dot2acc(v3.y, a1);
        a2 = dot2acc(v3.z, a2); a3 = dot2acc(v3.w, a3);
        a0 = dot2acc(v4.x, a0); a1 = dot2acc(v4.y, a1);
        a2 = dot2acc(v4.z, a2); a3 = dot2acc(v4.w, a3);
        a0 = dot2acc(v5.x, a0); a1 = dot2acc(v5.y, a1);
        a2 = dot2acc(v5.z, a2); a3 = dot2acc(v5.w, a3);
        a0 = dot2acc(v6.x, a0); a1 = dot2acc(v6.y, a1);
        a2 = dot2acc(v6.z, a2); a3 = dot2acc(v6.w, a3);
        a0 = dot2acc(v7.x, a0); a1 = dot2acc(v7.y, a1);
        a2 = dot2acc(v7.z, a2); a3 = dot2acc(v7.w, a3);
    }
    for (; e + 3 < end; e += 4) {
        int s0 = col[e], s1 = col[e + 1], s2 = col[e + 2], s3 = col[e + 3];
        uint4 v0 = *(const uint4*)(hsl + (unsigned)s0 * 16u);
        uint4 v1 = *(const uint4*)(hsl + (unsigned)s1 * 16u);
        uint4 v2 = *(const uint4*)(hsl + (unsigned)s2 * 16u);
        uint4 v3 = *(const uint4*)(hsl + (unsigned)s3 * 16u);
        a0 = dot2acc(v0.x, a0); a1 = dot2acc(v0.y, a1);
        a2 = dot2acc(v0.z, a2); a3 = dot2acc(v0.w, a3);
        a0 = dot2acc(v1.x, a0); a1 = dot2acc(v1.y, a1);
        a2 = dot2acc(v1.z, a2); a3 = dot2acc(v1.w, a3);
        a0 = dot2acc(v2.x, a0); a1 = dot2acc(v2.y, a1);
        a2 = dot2acc(v2.z, a2); a3 = dot2acc(v2.w, a3);
        a0 = dot2acc(v3.x, a0); a1 = dot2acc(v3.y, a1);
        a2 = dot2acc(v3.z, a2); a3 = dot2acc(v3.w, a3);
    }
    for (; e < end; ++e) {
        uint4 v0 = *(const uint4*)(hsl + (unsigned)col[e] * 16u);
        a0 = dot2acc(v0.x, a0); a1 = dot2acc(v0.y, a1);
        a2 = dot2acc(v0.z, a2); a3 = dot2acc(v0.w, a3);
    }
    const float di = deg_inv[node];
    uint4 r;
    r.x = pack_split(a0 * di);
    r.y = pack_split(a1 * di);
    r.z = pack_split(a2 * di);
    r.w = pack_split(a3 * di);
    *(uint4*)(mp + (size_t)slice * SL_STRIDE + (size_t)node * 16 + q4) = r;
}

// ---------------- MFMA GEMM, 2-tile register blocking ----------------
// 256 thr = 4 waves x 32 rows = 128 rows/block, 391 blocks, LDS 64KB (2/CU).

__device__ inline void unpk8(u32x8 p, half8& hi, half8& lo) {
    #pragma unroll
    for (int i = 0; i < 8; ++i) {
        PK t; t.u = p[i];
        hi[i] = t.h[0];
        lo[i] = t.h[1];
    }
}

__global__ __launch_bounds__(256, 2) void gemm_mfma(
        const u32* __restrict__ mean_pk, const u32* __restrict__ h_pk,
        const _Float16* __restrict__ Wlh, const _Float16* __restrict__ Wll,
        const _Float16* __restrict__ Wrh, const _Float16* __restrict__ Wrl,
        const float* __restrict__ bias,
        u32* __restrict__ out_pk, float* __restrict__ out_f32, int final_layer) {
    __shared__ char Wlds[65536];           // 2 mats x [128 j][128 k] fp16, swizzled
    const int t    = threadIdx.x;
    const int lane = t & 63;
    const int w    = t >> 6;               // 0..3
    const int jr   = lane & 15;
    const int q    = lane >> 4;

    const int basew = blockIdx.x * 128 + w * 32;
    int r0 = basew + jr;      if (r0 > N_NODES - 1) r0 = N_NODES - 1;
    int r1 = basew + 16 + jr; if (r1 > N_NODES - 1) r1 = N_NODES - 1;

    f32x4 accL0[8], accR0[8], accL1[8], accR1[8];
    #pragma unroll
    for (int jt = 0; jt < 8; ++jt) {
        accL0[jt] = (f32x4)(0.f); accR0[jt] = (f32x4)(0.f);
        accL1[jt] = (f32x4)(0.f); accR1[jt] = (f32x4)(0.f);
    }

    // ---- phase A: hi weights; cache hi-A in registers ----
    #pragma unroll
    for (int i = 0; i < 8; ++i) {
        int gi = t + i * 256;              // 2048 granules of 16B per matrix
        int j = gi >> 4, p = gi & 15;
        int dstb = j * 256 + ((p ^ (j & 7)) * 16);
        int srci = j * HID + p * 8;
        *(half8*)&Wlds[dstb]         = *(const half8*)(Wlh + srci);
        *(half8*)&Wlds[32768 + dstb] = *(const half8*)(Wrh + srci);
    }
    __syncthreads();

    half8 mhs0[4], hhs0[4], mhs1[4], hhs1[4];
    #pragma unroll
    for (int kk = 0; kk < 4; ++kk) {
        size_t a0 = ((size_t)(2 * kk + (q >> 1)) * N_NODES + r0) * 16 + (q & 1) * 8;
        size_t a1 = ((size_t)(2 * kk + (q >> 1)) * N_NODES + r1) * 16 + (q & 1) * 8;
        u32x8 m0 = *(const u32x8*)(mean_pk + a0);
        u32x8 h0 = *(const u32x8*)(h_pk + a0);
        u32x8 m1 = *(const u32x8*)(mean_pk + a1);
        u32x8 h1 = *(const u32x8*)(h_pk + a1);
        half8 mh0, ml0, hh0, hl0, mh1, ml1, hh1, hl1;
        unpk8(m0, mh0, ml0); unpk8(h0, hh0, hl0);
        unpk8(m1, mh1, ml1); unpk8(h1, hh1, hl1);
        mhs0[kk] = mh0; hhs0[kk] = hh0;
        mhs1[kk] = mh1; hhs1[kk] = hh1;
        #pragma unroll
        for (int jt = 0; jt < 8; ++jt) {
            int j  = jt * 16 + jr;
            int wb = j * 256 + (((kk * 4 + q) ^ (j & 7)) * 16);
            half8 wl = *(const half8*)&Wlds[wb];
            half8 wr = *(const half8*)&Wlds[32768 + wb];
            accL0[jt] = __builtin_amdgcn_mfma_f32_16x16x32_f16(mh0, wl, accL0[jt], 0, 0, 0);
            accL0[jt] = __builtin_amdgcn_mfma_f32_16x16x32_f16(ml0, wl, accL0[jt], 0, 0, 0);
            accR0[jt] = __builtin_amdgcn_mfma_f32_16x16x32_f16(hh0, wr, accR0[jt], 0, 0, 0);
            accR0[jt] = __builtin_amdgcn_mfma_f32_16x16x32_f16(hl0, wr, accR0[jt], 0, 0, 0);
            accL1[jt] = __builtin_amdgcn_mfma_f32_16x16x32_f16(mh1, wl, accL1[jt], 0, 0, 0);
            accL1[jt] = __builtin_amdgcn_mfma_f32_16x16x32_f16(ml1, wl, accL1[jt], 0, 0, 0);
            accR1[jt] = __builtin_amdgcn_mfma_f32_16x16x32_f16(hh1, wr, accR1[jt], 0, 0, 0);
            accR1[jt] = __builtin_amdgcn_mfma_f32_16x16x32_f16(hl1, wr, accR1[jt], 0, 0, 0);
        }
    }
    __syncthreads();

    // ---- phase B: lo weights; A-hi from registers ----
    #pragma unroll
    for (int i = 0; i < 8; ++i) {
        int gi = t + i * 256;
        int j = gi >> 4, p = gi & 15;
        int dstb = j * 256 + ((p ^ (j & 7)) * 16);
        int srci = j * HID + p * 8;
        *(half8*)&Wlds[dstb]         = *(const half8*)(Wll + srci);
        *(half8*)&Wlds[32768 + dstb] = *(const half8*)(Wrl + srci);
    }
    __syncthreads();
    #pragma unroll
    for (int kk = 0; kk < 4; ++kk) {
        half8 mh0 = mhs0[kk], hh0 = hhs0[kk];
        half8 mh1 = mhs1[kk], hh1 = hhs1[kk];
        #pragma unroll
        for (int jt = 0; jt < 8; ++jt) {
            int j  = jt * 16 + jr;
            int wb = j * 256 + (((kk * 4 + q) ^ (j & 7)) * 16);
            half8 wl = *(const half8*)&Wlds[wb];
            half8 wr = *(const half8*)&Wlds[32768 + wb];
            accL0[jt] = __builtin_amdgcn_mfma_f32_16x16x32_f16(mh0, wl, accL0[jt], 0, 0, 0);
            accR0[jt] = __builtin_amdgcn_mfma_f32_16x16x32_f16(hh0, wr, accR0[jt], 0, 0, 0);
            accL1[jt] = __builtin_amdgcn_mfma_f32_16x16x32_f16(mh1, wl, accL1[jt], 0, 0, 0);
            accR1[jt] = __builtin_amdgcn_mfma_f32_16x16x32_f16(hh1, wr, accR1[jt], 0, 0, 0);
        }
    }

    // ---- epilogue: C/D row=(lane>>4)*4+g, col=lane&15 ----
    float bv[8];
    #pragma unroll
    for (int jt = 0; jt < 8; ++jt) bv[jt] = bias[jt * 16 + jr];

    #pragma unroll
    for (int jt = 0; jt < 8; ++jt) {
        #pragma unroll
        for (int g = 0; g < 4; ++g) {
            int row = basew + q * 4 + g;
            if (row < N_NODES) {
                float v = accL0[jt][g] + accR0[jt][g] + bv[jt];
                if (final_layer) {
                    out_f32[(size_t)row * HID + jt * 16 + jr] = v;
                } else {
                    out_pk[((size_t)jt * N_NODES + row) * 16 + jr] =
                        pack_split(fmaxf(v, 0.f));
                }
            }
            int row2 = basew + 16 + q * 4 + g;
            if (row2 < N_NODES) {
                float v = accL1[jt][g] + accR1[jt][g] + bv[jt];
                if (final_layer) {
                    out_f32[(size_t)row2 * HID + jt * 16 + jr] = v;
                } else {
                    out_pk[((size_t)jt * N_NODES + row2) * 16 + jr] =
                        pack_split(fmaxf(v, 0.f));
                }
            }
        }
    }
}

// ---------------- launch ----------------

extern "C" void kernel_launch(void* const* d_in, const int* in_sizes, int n_in,
                              void* d_out, int out_size, void* d_ws, size_t ws_size,
                              hipStream_t stream) {
    const float* x    = (const float*)d_in[0];
    const int*   edge = (const int*)d_in[1];
    const float* Wl   = (const float*)d_in[2];
    const float* Wr   = (const float*)d_in[3];
    const float* bias = (const float*)d_in[4];
    float* out = (float*)d_out;

    u32* h_pk    = (u32*)d_ws;                    // 25.6 MB, slice-major
    u32* mean_pk = h_pk + NH;                     // 25.6 MB, slice-major
    _Float16* Wlh = (_Float16*)(mean_pk + NH);
    _Float16* Wll = Wlh + 81920;
    _Float16* Wrh = Wll + 81920;
    _Float16* Wrl = Wrh + 81920;
    float* deg_inv = (float*)(Wrl + 81920);
    int*   deg     = (int*)(deg_inv + N_NODES);
    int*   row_ptr = deg + N_NODES;
    int*   cursor  = row_ptr + (N_NODES + 1);
    int*   colarr  = cursor + N_NODES;
    int*   blk_sums  = colarr + N_EDGES;
    int*   blk_off   = blk_sums + N_SCAN_BLOCKS;
    int*   hist      = blk_off + N_SCAN_BLOCKS;   // 256
    int*   bin_cur   = hist + 256;                // 256
    int*   node_perm = bin_cur + 256;             // 50K

    const int* src = edge;
    const int* dst = edge + N_EDGES;

    zero_deg<<<N_SCAN_BLOCKS, SCAN_BLK, 0, stream>>>(deg, hist);
    deg_count<<<(N_EDGES + 255) / 256, 256, 0, stream>>>(dst, deg);
    deg_reduce<<<N_SCAN_BLOCKS, SCAN_BLK, 0, stream>>>(deg, blk_sums);
    scan_partials<<<1, SCAN_BLK, 0, stream>>>(blk_sums, blk_off);
    scan_write<<<N_SCAN_BLOCKS, SCAN_BLK, 0, stream>>>(deg, blk_off, row_ptr,
                                                       cursor, deg_inv, hist);
    hist_scan<<<1, 256, 0, stream>>>(hist, bin_cur);
    perm_scatter<<<N_SCAN_BLOCKS, SCAN_BLK, 0, stream>>>(deg, bin_cur, node_perm);
    fill_csr<<<(N_EDGES + 255) / 256, 256, 0, stream>>>(src, dst, cursor, colarr);

    const int split_units = 2 * W_N4 + X_Q;       // 1,640,960
    split_all<<<(split_units + 255) / 256, 256, 0, stream>>>(
        Wl, Wr, x, Wlh, Wll, Wrh, Wrl, h_pk);

    const int agg_blocks = ((N_NODES + 63) / 64) * NSLICE;   // 6256
    const int gemm_blocks = (N_NODES + 127) / 128;           // 391

    for (int l = 0; l < N_LAYERS; ++l) {
        aggregate_d2<<<agg_blocks, 256, 0, stream>>>(
            h_pk, row_ptr, colarr, node_perm, deg_inv, mean_pk);
        gemm_mfma<<<gemm_blocks, 256, 0, stream>>>(
            mean_pk, h_pk,
            Wlh + (size_t)l * 16384, Wll + (size_t)l * 16384,
            Wrh + (size_t)l * 16384, Wrl + (size_t)l * 16384,
            bias + (size_t)l * HID,
            h_pk, out, (l == N_LAYERS - 1) ? 1 : 0);
    }
}

// Round 16
// 364.007 us; speedup vs baseline: 2.0141x; 2.0141x over previous
//
#include <hip/hip_runtime.h>

#define N_NODES 50000
#define N_EDGES 600000
#define HID 128
#define N_LAYERS 5
#define SCAN_BLK 256
#define N_SCAN_BLOCKS ((N_NODES + SCAN_BLK - 1) / SCAN_BLK)   // 196
#define NH ((size_t)N_NODES * HID)
#define NSLICE 8
#define SL_STRIDE ((size_t)N_NODES * 16)   // u32 per slice

typedef unsigned int u32;
typedef _Float16 half8 __attribute__((ext_vector_type(8)));
typedef _Float16 half4 __attribute__((ext_vector_type(4)));
typedef _Float16 h2 __attribute__((ext_vector_type(2)));
typedef float f32x4 __attribute__((ext_vector_type(4)));
typedef u32 u32x8 __attribute__((ext_vector_type(8)));

// packed split format: one u32 per feature; h[0]=fp16 hi, h[1]=fp16 residual
union PK { u32 u; _Float16 h[2]; };

__device__ inline u32 pack_split(float v) {
    PK r;
    r.h[0] = (_Float16)v;
    r.h[1] = (_Float16)(v - (float)r.h[0]);
    return r.u;
}
// acc += hi + lo in ONE VALU op: v_dot2_f32_f16 with b=(1,1)
__device__ inline float dot2acc(u32 p, float acc) {
    h2 a = __builtin_bit_cast(h2, p);
    h2 ones; ones[0] = (_Float16)1.0f; ones[1] = (_Float16)1.0f;
    return __builtin_amdgcn_fdot2(a, ones, acc, false);
}

// ---------------- CSR build ----------------

__global__ void zero_deg(int* __restrict__ deg) {
    int i = blockIdx.x * blockDim.x + threadIdx.x;
    if (i < N_NODES) deg[i] = 0;
}

__global__ void deg_count(const int* __restrict__ dst, int* __restrict__ deg) {
    int e = blockIdx.x * blockDim.x + threadIdx.x;
    if (e < N_EDGES) atomicAdd(&deg[dst[e]], 1);
}

__global__ __launch_bounds__(SCAN_BLK) void deg_reduce(const int* __restrict__ deg,
                                                       int* __restrict__ block_sums) {
    __shared__ int s[SCAN_BLK];
    int i = blockIdx.x * SCAN_BLK + threadIdx.x;
    int v = (i < N_NODES) ? deg[i] : 0;
    s[threadIdx.x] = v;
    __syncthreads();
    for (int off = SCAN_BLK / 2; off > 0; off >>= 1) {
        if (threadIdx.x < off) s[threadIdx.x] += s[threadIdx.x + off];
        __syncthreads();
    }
    if (threadIdx.x == 0) block_sums[blockIdx.x] = s[0];
}

__global__ __launch_bounds__(SCAN_BLK) void scan_partials(const int* __restrict__ block_sums,
                                                          int* __restrict__ block_off) {
    __shared__ int s[SCAN_BLK];
    int t = threadIdx.x;
    int v = (t < N_SCAN_BLOCKS) ? block_sums[t] : 0;
    s[t] = v;
    __syncthreads();
    for (int off = 1; off < SCAN_BLK; off <<= 1) {
        int u = (t >= off) ? s[t - off] : 0;
        __syncthreads();
        s[t] += u;
        __syncthreads();
    }
    if (t < N_SCAN_BLOCKS) block_off[t] = s[t] - v;
}

__global__ __launch_bounds__(SCAN_BLK) void scan_write(const int* __restrict__ deg,
        const int* __restrict__ block_off, int* __restrict__ row_ptr,
        int* __restrict__ cursor, float* __restrict__ deg_inv) {
    __shared__ int s[SCAN_BLK];
    int t = threadIdx.x;
    int i = blockIdx.x * SCAN_BLK + t;
    int v = (i < N_NODES) ? deg[i] : 0;
    s[t] = v;
    __syncthreads();
    for (int off = 1; off < SCAN_BLK; off <<= 1) {
        int u = (t >= off) ? s[t - off] : 0;
        __syncthreads();
        s[t] += u;
        __syncthreads();
    }
    int excl = s[t] - v + block_off[blockIdx.x];
    if (i < N_NODES) {
        row_ptr[i] = excl;
        cursor[i]  = excl;
        deg_inv[i] = 1.0f / (float)max(v, 1);
    }
    if (i == N_NODES) row_ptr[N_NODES] = excl;
}

__global__ void fill_csr(const int* __restrict__ src, const int* __restrict__ dst,
                         int* __restrict__ cursor, int* __restrict__ col) {
    int e = blockIdx.x * blockDim.x + threadIdx.x;
    if (e < N_EDGES) {
        int d = dst[e];
        int pos = atomicAdd(&cursor[d], 1);
        col[pos] = src[e];
    }
}

// ---------------- merged split kernel ----------------
#define W_N4 20480
#define X_Q 1600000

__global__ void split_all(const float* __restrict__ Wl, const float* __restrict__ Wr,
                          const float* __restrict__ x,
                          _Float16* __restrict__ Wlh, _Float16* __restrict__ Wll,
                          _Float16* __restrict__ Wrh, _Float16* __restrict__ Wrl,
                          u32* __restrict__ hp) {
    int i = blockIdx.x * blockDim.x + threadIdx.x;
    if (i < 2 * W_N4) {
        const float* srcp = (i < W_N4) ? Wl : Wr;
        _Float16* hi = (i < W_N4) ? Wlh : Wrh;
        _Float16* lo = (i < W_N4) ? Wll : Wrl;
        int k = (i < W_N4) ? i : i - W_N4;
        float4 v = *(const float4*)(srcp + (size_t)k * 4);
        half4 h, l;
        h.x = (_Float16)v.x; l.x = (_Float16)(v.x - (float)h.x);
        h.y = (_Float16)v.y; l.y = (_Float16)(v.y - (float)h.y);
        h.z = (_Float16)v.z; l.z = (_Float16)(v.z - (float)h.z);
        h.w = (_Float16)v.w; l.w = (_Float16)(v.w - (float)h.w);
        *(half4*)(hi + (size_t)k * 4) = h;
        *(half4*)(lo + (size_t)k * 4) = l;
    } else {
        int iq = i - 2 * W_N4;
        if (iq >= X_Q) return;
        int n = iq >> 5;          // node
        int c = iq & 31;          // quad within row
        float4 v = *(const float4*)(x + (size_t)n * HID + c * 4);
        uint4 r;
        r.x = pack_split(v.x); r.y = pack_split(v.y);
        r.z = pack_split(v.z); r.w = pack_split(v.w);
        int slice = c >> 2, rem = (c & 3) * 4;
        *(uint4*)(hp + (size_t)slice * SL_STRIDE + (size_t)n * 16 + rem) = r;
    }
}

// ---- slice-major mean aggregation: 4-lane group per (node,slice) ----
// Lane q owns u32s [4q,4q+4); 8-deep edge unroll (8 gathers in flight),
// v_dot2_f32_f16 accumulate. No cross-lane ops.
// slice = blockIdx&7 -> XCD pinning: each XCD's L2 caches one 3.2MB slice.

__global__ __launch_bounds__(256) void aggregate_d2(const u32* __restrict__ hp,
        const int* __restrict__ row_ptr, const int* __restrict__ col,
        const float* __restrict__ deg_inv, u32* __restrict__ mp) {
    const int wave  = threadIdx.x >> 6;
    const int lane  = threadIdx.x & 63;
    const int grp   = lane >> 2;          // 16 node-groups per wave
    const int q4    = (lane & 3) * 4;     // u32 offset of this lane's quad
    const int slice = blockIdx.x & 7;
    const int node  = (blockIdx.x >> 3) * 64 + wave * 16 + grp;
    if (node >= N_NODES) return;
    const u32* hsl = hp + (size_t)slice * SL_STRIDE + q4;
    const int beg = row_ptr[node], end = row_ptr[node + 1];
    float a0 = 0.f, a1 = 0.f, a2 = 0.f, a3 = 0.f;
    int e = beg;
    for (; e + 7 < end; e += 8) {         // 8 row-lines in flight per group
        int s0 = col[e],     s1 = col[e + 1], s2 = col[e + 2], s3 = col[e + 3];
        int s4 = col[e + 4], s5 = col[e + 5], s6 = col[e + 6], s7 = col[e + 7];
        uint4 v0 = *(const uint4*)(hsl + (unsigned)s0 * 16u);
        uint4 v1 = *(const uint4*)(hsl + (unsigned)s1 * 16u);
        uint4 v2 = *(const uint4*)(hsl + (unsigned)s2 * 16u);
        uint4 v3 = *(const uint4*)(hsl + (unsigned)s3 * 16u);
        uint4 v4 = *(const uint4*)(hsl + (unsigned)s4 * 16u);
        uint4 v5 = *(const uint4*)(hsl + (unsigned)s5 * 16u);
        uint4 v6 = *(const uint4*)(hsl + (unsigned)s6 * 16u);
        uint4 v7 = *(const uint4*)(hsl + (unsigned)s7 * 16u);
        a0 = dot2acc(v0.x, a0); a1 = dot2acc(v0.y, a1);
        a2 = dot2acc(v0.z, a2); a3 = dot2acc(v0.w, a3);
        a0 = dot2acc(v1.x, a0); a1 = dot2acc(v1.y, a1);
        a2 = dot2acc(v1.z, a2); a3 = dot2acc(v1.w, a3);
        a0 = dot2acc(v2.x, a0); a1 = dot2acc(v2.y, a1);
        a2 = dot2acc(v2.z, a2); a3 = dot2acc(v2.w, a3);
        a0 = dot2acc(v3.x, a0); a1 = dot2acc(v3.y, a1);
        a2 = dot2acc(v3.z, a2); a3 = dot2acc(v3.w, a3);
        a0 = dot2acc(v4.x, a0); a1 = dot2acc(v4.y, a1);
        a2 = dot2acc(v4.z, a2); a3 = dot2acc(v4.w, a3);
        a0 = dot2acc(v5.x, a0); a1 = dot2acc(v5.y, a1);
        a2 = dot2acc(v5.z, a2); a3 = dot2acc(v5.w, a3);
        a0 = dot2acc(v6.x, a0); a1 = dot2acc(v6.y, a1);
        a2 = dot2acc(v6.z, a2); a3 = dot2acc(v6.w, a3);
        a0 = dot2acc(v7.x, a0); a1 = dot2acc(v7.y, a1);
        a2 = dot2acc(v7.z, a2); a3 = dot2acc(v7.w, a3);
    }
    for (; e + 3 < end; e += 4) {
        int s0 = col[e], s1 = col[e + 1], s2 = col[e + 2], s3 = col[e + 3];
        uint4 v0 = *(const uint4*)(hsl + (unsigned)s0 * 16u);
        uint4 v1 = *(const uint4*)(hsl + (unsigned)s1 * 16u);
        uint4 v2 = *(const uint4*)(hsl + (unsigned)s2 * 16u);
        uint4 v3 = *(const uint4*)(hsl + (unsigned)s3 * 16u);
        a0 = dot2acc(v0.x, a0); a1 = dot2acc(v0.y, a1);
        a2 = dot2acc(v0.z, a2); a3 = dot2acc(v0.w, a3);
        a0 = dot2acc(v1.x, a0); a1 = dot2acc(v1.y, a1);
        a2 = dot2acc(v1.z, a2); a3 = dot2acc(v1.w, a3);
        a0 = dot2acc(v2.x, a0); a1 = dot2acc(v2.y, a1);
        a2 = dot2acc(v2.z, a2); a3 = dot2acc(v2.w, a3);
        a0 = dot2acc(v3.x, a0); a1 = dot2acc(v3.y, a1);
        a2 = dot2acc(v3.z, a2); a3 = dot2acc(v3.w, a3);
    }
    for (; e < end; ++e) {
        uint4 v0 = *(const uint4*)(hsl + (unsigned)col[e] * 16u);
        a0 = dot2acc(v0.x, a0); a1 = dot2acc(v0.y, a1);
        a2 = dot2acc(v0.z, a2); a3 = dot2acc(v0.w, a3);
    }
    const float di = deg_inv[node];
    uint4 r;
    r.x = pack_split(a0 * di);
    r.y = pack_split(a1 * di);
    r.z = pack_split(a2 * di);
    r.w = pack_split(a3 * di);
    *(uint4*)(mp + (size_t)slice * SL_STRIDE + (size_t)node * 16 + q4) = r;
}

// ---------------- MFMA GEMM, 2-tile register blocking ----------------
// 256 thr = 4 waves x 32 rows = 128 rows/block, 391 blocks, LDS 64KB (2/CU).
// Each W ds_read feeds 8 MFMAs (2 output tiles) -> LDS-read per tile halved.
// Phase A loads A once; hi parts kept in registers for phase B.

__device__ inline void unpk8(u32x8 p, half8& hi, half8& lo) {
    #pragma unroll
    for (int i = 0; i < 8; ++i) {
        PK t; t.u = p[i];
        hi[i] = t.h[0];
        lo[i] = t.h[1];
    }
}

__global__ __launch_bounds__(256, 2) void gemm_mfma(
        const u32* __restrict__ mean_pk, const u32* __restrict__ h_pk,
        const _Float16* __restrict__ Wlh, const _Float16* __restrict__ Wll,
        const _Float16* __restrict__ Wrh, const _Float16* __restrict__ Wrl,
        const float* __restrict__ bias,
        u32* __restrict__ out_pk, float* __restrict__ out_f32, int final_layer) {
    __shared__ char Wlds[65536];           // 2 mats x [128 j][128 k] fp16, swizzled
    const int t    = threadIdx.x;
    const int lane = t & 63;
    const int w    = t >> 6;               // 0..3
    const int jr   = lane & 15;
    const int q    = lane >> 4;

    const int basew = blockIdx.x * 128 + w * 32;
    int r0 = basew + jr;      if (r0 > N_NODES - 1) r0 = N_NODES - 1;
    int r1 = basew + 16 + jr; if (r1 > N_NODES - 1) r1 = N_NODES - 1;

    f32x4 accL0[8], accR0[8], accL1[8], accR1[8];
    #pragma unroll
    for (int jt = 0; jt < 8; ++jt) {
        accL0[jt] = (f32x4)(0.f); accR0[jt] = (f32x4)(0.f);
        accL1[jt] = (f32x4)(0.f); accR1[jt] = (f32x4)(0.f);
    }

    // ---- phase A: hi weights; cache hi-A in registers ----
    #pragma unroll
    for (int i = 0; i < 8; ++i) {
        int gi = t + i * 256;              // 2048 granules of 16B per matrix
        int j = gi >> 4, p = gi & 15;
        int dstb = j * 256 + ((p ^ (j & 7)) * 16);
        int srci = j * HID + p * 8;
        *(half8*)&Wlds[dstb]         = *(const half8*)(Wlh + srci);
        *(half8*)&Wlds[32768 + dstb] = *(const half8*)(Wrh + srci);
    }
    __syncthreads();

    half8 mhs0[4], hhs0[4], mhs1[4], hhs1[4];
    #pragma unroll
    for (int kk = 0; kk < 4; ++kk) {
        size_t a0 = ((size_t)(2 * kk + (q >> 1)) * N_NODES + r0) * 16 + (q & 1) * 8;
        size_t a1 = ((size_t)(2 * kk + (q >> 1)) * N_NODES + r1) * 16 + (q & 1) * 8;
        u32x8 m0 = *(const u32x8*)(mean_pk + a0);
        u32x8 h0 = *(const u32x8*)(h_pk + a0);
        u32x8 m1 = *(const u32x8*)(mean_pk + a1);
        u32x8 h1 = *(const u32x8*)(h_pk + a1);
        half8 mh0, ml0, hh0, hl0, mh1, ml1, hh1, hl1;
        unpk8(m0, mh0, ml0); unpk8(h0, hh0, hl0);
        unpk8(m1, mh1, ml1); unpk8(h1, hh1, hl1);
        mhs0[kk] = mh0; hhs0[kk] = hh0;
        mhs1[kk] = mh1; hhs1[kk] = hh1;
        #pragma unroll
        for (int jt = 0; jt < 8; ++jt) {
            int j  = jt * 16 + jr;
            int wb = j * 256 + (((kk * 4 + q) ^ (j & 7)) * 16);
            half8 wl = *(const half8*)&Wlds[wb];
            half8 wr = *(const half8*)&Wlds[32768 + wb];
            accL0[jt] = __builtin_amdgcn_mfma_f32_16x16x32_f16(mh0, wl, accL0[jt], 0, 0, 0);
            accL0[jt] = __builtin_amdgcn_mfma_f32_16x16x32_f16(ml0, wl, accL0[jt], 0, 0, 0);
            accR0[jt] = __builtin_amdgcn_mfma_f32_16x16x32_f16(hh0, wr, accR0[jt], 0, 0, 0);
            accR0[jt] = __builtin_amdgcn_mfma_f32_16x16x32_f16(hl0, wr, accR0[jt], 0, 0, 0);
            accL1[jt] = __builtin_amdgcn_mfma_f32_16x16x32_f16(mh1, wl, accL1[jt], 0, 0, 0);
            accL1[jt] = __builtin_amdgcn_mfma_f32_16x16x32_f16(ml1, wl, accL1[jt], 0, 0, 0);
            accR1[jt] = __builtin_amdgcn_mfma_f32_16x16x32_f16(hh1, wr, accR1[jt], 0, 0, 0);
            accR1[jt] = __builtin_amdgcn_mfma_f32_16x16x32_f16(hl1, wr, accR1[jt], 0, 0, 0);
        }
    }
    __syncthreads();

    // ---- phase B: lo weights; A-hi from registers ----
    #pragma unroll
    for (int i = 0; i < 8; ++i) {
        int gi = t + i * 256;
        int j = gi >> 4, p = gi & 15;
        int dstb = j * 256 + ((p ^ (j & 7)) * 16);
        int srci = j * HID + p * 8;
        *(half8*)&Wlds[dstb]         = *(const half8*)(Wll + srci);
        *(half8*)&Wlds[32768 + dstb] = *(const half8*)(Wrl + srci);
    }
    __syncthreads();
    #pragma unroll
    for (int kk = 0; kk < 4; ++kk) {
        half8 mh0 = mhs0[kk], hh0 = hhs0[kk];
        half8 mh1 = mhs1[kk], hh1 = hhs1[kk];
        #pragma unroll
        for (int jt = 0; jt < 8; ++jt) {
            int j  = jt * 16 + jr;
            int wb = j * 256 + (((kk * 4 + q) ^ (j & 7)) * 16);
            half8 wl = *(const half8*)&Wlds[wb];
            half8 wr = *(const half8*)&Wlds[32768 + wb];
            accL0[jt] = __builtin_amdgcn_mfma_f32_16x16x32_f16(mh0, wl, accL0[jt], 0, 0, 0);
            accR0[jt] = __builtin_amdgcn_mfma_f32_16x16x32_f16(hh0, wr, accR0[jt], 0, 0, 0);
            accL1[jt] = __builtin_amdgcn_mfma_f32_16x16x32_f16(mh1, wl, accL1[jt], 0, 0, 0);
            accR1[jt] = __builtin_amdgcn_mfma_f32_16x16x32_f16(hh1, wr, accR1[jt], 0, 0, 0);
        }
    }

    // ---- epilogue: C/D row=(lane>>4)*4+g, col=lane&15 ----
    float bv[8];
    #pragma unroll
    for (int jt = 0; jt < 8; ++jt) bv[jt] = bias[jt * 16 + jr];

    #pragma unroll
    for (int jt = 0; jt < 8; ++jt) {
        #pragma unroll
        for (int g = 0; g < 4; ++g) {
            int row = basew + q * 4 + g;
            if (row < N_NODES) {
                float v = accL0[jt][g] + accR0[jt][g] + bv[jt];
                if (final_layer) {
                    out_f32[(size_t)row * HID + jt * 16 + jr] = v;
                } else {
                    out_pk[((size_t)jt * N_NODES + row) * 16 + jr] =
                        pack_split(fmaxf(v, 0.f));
                }
            }
            int row2 = basew + 16 + q * 4 + g;
            if (row2 < N_NODES) {
                float v = accL1[jt][g] + accR1[jt][g] + bv[jt];
                if (final_layer) {
                    out_f32[(size_t)row2 * HID + jt * 16 + jr] = v;
                } else {
                    out_pk[((size_t)jt * N_NODES + row2) * 16 + jr] =
                        pack_split(fmaxf(v, 0.f));
                }
            }
        }
    }
}

// ---------------- launch ----------------

extern "C" void kernel_launch(void* const* d_in, const int* in_sizes, int n_in,
                              void* d_out, int out_size, void* d_ws, size_t ws_size,
                              hipStream_t stream) {
    const float* x    = (const float*)d_in[0];
    const int*   edge = (const int*)d_in[1];
    const float* Wl   = (const float*)d_in[2];
    const float* Wr   = (const float*)d_in[3];
    const float* bias = (const float*)d_in[4];
    float* out = (float*)d_out;

    u32* h_pk    = (u32*)d_ws;                    // 25.6 MB, slice-major
    u32* mean_pk = h_pk + NH;                     // 25.6 MB, slice-major
    _Float16* Wlh = (_Float16*)(mean_pk + NH);
    _Float16* Wll = Wlh + 81920;
    _Float16* Wrh = Wll + 81920;
    _Float16* Wrl = Wrh + 81920;
    float* deg_inv = (float*)(Wrl + 81920);
    int*   deg     = (int*)(deg_inv + N_NODES);
    int*   row_ptr = deg + N_NODES;
    int*   cursor  = row_ptr + (N_NODES + 1);
    int*   colarr  = cursor + N_NODES;
    int*   blk_sums = colarr + N_EDGES;
    int*   blk_off  = blk_sums + N_SCAN_BLOCKS;

    const int* src = edge;
    const int* dst = edge + N_EDGES;

    zero_deg<<<N_SCAN_BLOCKS, SCAN_BLK, 0, stream>>>(deg);
    deg_count<<<(N_EDGES + 255) / 256, 256, 0, stream>>>(dst, deg);
    deg_reduce<<<N_SCAN_BLOCKS, SCAN_BLK, 0, stream>>>(deg, blk_sums);
    scan_partials<<<1, SCAN_BLK, 0, stream>>>(blk_sums, blk_off);
    scan_write<<<N_SCAN_BLOCKS, SCAN_BLK, 0, stream>>>(deg, blk_off, row_ptr,
                                                       cursor, deg_inv);
    fill_csr<<<(N_EDGES + 255) / 256, 256, 0, stream>>>(src, dst, cursor, colarr);

    const int split_units = 2 * W_N4 + X_Q;       // 1,640,960
    split_all<<<(split_units + 255) / 256, 256, 0, stream>>>(
        Wl, Wr, x, Wlh, Wll, Wrh, Wrl, h_pk);

    const int agg_blocks = ((N_NODES + 63) / 64) * NSLICE;   // 6256
    const int gemm_blocks = (N_NODES + 127) / 128;           // 391

    for (int l = 0; l < N_LAYERS; ++l) {
        aggregate_d2<<<agg_blocks, 256, 0, stream>>>(
            h_pk, row_ptr, colarr, deg_inv, mean_pk);
        gemm_mfma<<<gemm_blocks, 256, 0, stream>>>(
            mean_pk, h_pk,
            Wlh + (size_t)l * 16384, Wll + (size_t)l * 16384,
            Wrh + (size_t)l * 16384, Wrl + (size_t)l * 16384,
            bias + (size_t)l * HID,
            h_pk, out, (l == N_LAYERS - 1) ? 1 : 0);
    }
}